// Round 15
// baseline (3099.611 us; speedup 1.0000x reference)
//
#include <hip/hip_runtime.h>
#include <math.h>

#define BB 64
#define TT 512
#define II 64
#define HH 512
#define NBPL 32          // blocks per layer (16 h-units each)
#define NBLK 96
#define FLAG_STRIDE 32   // dwords = 128 B between flags

typedef __attribute__((ext_vector_type(8))) _Float16 f16x8;
typedef __attribute__((ext_vector_type(16))) float f32x16;

__device__ __forceinline__ float sigmoidf_(float x) {
    return 1.0f / (1.0f + expf(-x));
}

// --- coherent scalar primitives (compiler-tracked) ---
__device__ __forceinline__ void store8_thru(void* p, unsigned long long u) {
    __hip_atomic_store((unsigned long long*)p, u, __ATOMIC_RELAXED, __HIP_MEMORY_SCOPE_AGENT);
}
__device__ __forceinline__ void storef_thru(float* p, float v) {
    __hip_atomic_store(p, v, __ATOMIC_RELAXED, __HIP_MEMORY_SCOPE_AGENT);
}
__device__ __forceinline__ float loadf_byp(const float* p) {
    return __hip_atomic_load(p, __ATOMIC_RELAXED, __HIP_MEMORY_SCOPE_AGENT);
}
__device__ __forceinline__ void storeu_thru(unsigned* p, unsigned v) {
    __hip_atomic_store(p, v, __ATOMIC_RELAXED, __HIP_MEMORY_SCOPE_AGENT);
}
__device__ __forceinline__ unsigned loadu_byp(const unsigned* p) {
    return __hip_atomic_load(p, __ATOMIC_RELAXED, __HIP_MEMORY_SCOPE_AGENT);
}

// Wave-parallel poll over 32 spread flags (lanes 32-63 mirror 0-31).
__device__ __forceinline__ void poll_ge32(const unsigned* flags, unsigned tgt) {
    const int lane = threadIdx.x & 31;
    const unsigned* a = flags + (size_t)lane * FLAG_STRIDE;
    unsigned f = loadu_byp(a);
    while (__ballot(f < tgt) != 0ull) {
        __builtin_amdgcn_s_sleep(1);
        f = loadu_byp(a);
    }
}

// --- 16B-bypass batched loads: 8 ksteps = 8 dwordx4, stride 2048B ---
struct B8 { f16x8 v0, v1, v2, v3, v4, v5, v6, v7; };

__device__ __forceinline__ void issue8(const char* rb, B8& b) {
    const char* p0 = rb;
    const char* p1 = rb + 2048;
    const char* p2 = rb + 4096;
    const char* p3 = rb + 6144;
    const char* p4 = rb + 8192;
    const char* p5 = rb + 10240;
    const char* p6 = rb + 12288;
    const char* p7 = rb + 14336;
    asm volatile(
        "global_load_dwordx4 %0, %8, off sc0 sc1\n\t"
        "global_load_dwordx4 %1, %9, off sc0 sc1\n\t"
        "global_load_dwordx4 %2, %10, off sc0 sc1\n\t"
        "global_load_dwordx4 %3, %11, off sc0 sc1\n\t"
        "global_load_dwordx4 %4, %12, off sc0 sc1\n\t"
        "global_load_dwordx4 %5, %13, off sc0 sc1\n\t"
        "global_load_dwordx4 %6, %14, off sc0 sc1\n\t"
        "global_load_dwordx4 %7, %15, off sc0 sc1"
        : "=&v"(b.v0), "=&v"(b.v1), "=&v"(b.v2), "=&v"(b.v3),
          "=&v"(b.v4), "=&v"(b.v5), "=&v"(b.v6), "=&v"(b.v7)
        : "v"(p0), "v"(p1), "v"(p2), "v"(p3), "v"(p4), "v"(p5), "v"(p6), "v"(p7));
}

// Counted waits; staged values tied through the asm (+sched_barrier, rule #18).
#define DEF_WAIT(NAME, CNT) \
__device__ __forceinline__ void NAME(B8& b) { \
    asm volatile("s_waitcnt vmcnt(" #CNT ")" \
        : "+v"(b.v0), "+v"(b.v1), "+v"(b.v2), "+v"(b.v3), \
          "+v"(b.v4), "+v"(b.v5), "+v"(b.v6), "+v"(b.v7)); \
    __builtin_amdgcn_sched_barrier(0); \
}
DEF_WAIT(wait16, 16)
DEF_WAIT(wait8, 8)
DEF_WAIT(wait0, 0)

#define MFMA_F16 __builtin_amdgcn_mfma_f32_32x32x16_f16

// 2 m-tiles per kstep: A0 at +0, A1 at +1024 within the 2048B kstep group.
template<int S0>
__device__ __forceinline__ void consume8(const char* wa, const B8& b,
                                         f32x16& c0, f32x16& c1) {
#define KSTEP(J, BV) { \
    f16x8 a0 = *(const f16x8*)(wa + (size_t)(S0 + J) * 2048); \
    f16x8 a1 = *(const f16x8*)(wa + (size_t)(S0 + J) * 2048 + 1024); \
    c0 = MFMA_F16(a0, BV, c0, 0, 0, 0); \
    c1 = MFMA_F16(a1, BV, c1, 0, 0, 0); }
    KSTEP(0, b.v0) KSTEP(1, b.v1) KSTEP(2, b.v2) KSTEP(3, b.v3)
    KSTEP(4, b.v4) KSTEP(5, b.v5) KSTEP(6, b.v6) KSTEP(7, b.v7)
#undef KSTEP
}

// 32-kstep panel, 3 batches (24 loads) in flight.
template<int S0>
__device__ __forceinline__ void panel32(const char* rb, const char* wa,
                                        f32x16& c0, f32x16& c1) {
    B8 A, B, C;
    issue8(rb, A);
    issue8(rb + 16384, B);
    issue8(rb + 32768, C);
    wait16(A); consume8<S0>(wa, A, c0, c1);
    issue8(rb + 49152, A);
    wait16(B); consume8<S0 + 8>(wa, B, c0, c1);
    wait8(C);  consume8<S0 + 16>(wa, C, c0, c1);
    wait0(A);  consume8<S0 + 24>(wa, A, c0, c1);
}
template<int S0>
__device__ __forceinline__ void panel16(const char* rb, const char* wa,
                                        f32x16& c0, f32x16& c1) {
    B8 A, B;
    issue8(rb, A);
    issue8(rb + 16384, B);
    wait8(A); consume8<S0>(wa, A, c0, c1);
    wait0(B); consume8<S0 + 8>(wa, B, c0, c1);
}

// x [B,T,I] -> xTq [t][grp=8][b=64][16B f16]
__global__ __launch_bounds__(256) void pack_x(const float* __restrict__ x,
                                              char* __restrict__ xTq) {
    const int t = blockIdx.x;
    const int b = threadIdx.x & 63;
    const int gq = threadIdx.x >> 6;
    #pragma unroll
    for (int gi = 0; gi < 2; ++gi) {
        const int g2 = gq + gi * 4;
        const float* src = x + ((size_t)b * TT + t) * II + g2 * 8;
        float w[8];
        *(float4*)&w[0] = *(const float4*)src;
        *(float4*)&w[4] = *(const float4*)(src + 4);
        f16x8 hv;
        #pragma unroll
        for (int j = 0; j < 8; ++j) hv[j] = (_Float16)w[j];
        *(f16x8*)(xTq + (((size_t)t * 8 + g2) * 64 + b) * 16) = hv;
    }
}

// Pack 64 gate-rows (2 m-tiles of 32) into LDS, f16 hi-only.
// WA[s][m][lane] 16B: dst = s*2048 + m*1024 + lane*16.
// m-tile m row r (= lane&31): gate = r>>3, hu = m*8 + (r&7).
template<int IN_DIM, int NKS>
__device__ void pack_weights(const float* __restrict__ Wih, const float* __restrict__ Whh,
                             int hbase16, char* __restrict__ WAc) {
    const int lane = threadIdx.x & 63;
    const int wq = threadIdx.x >> 6;
    const int r = lane & 31;
    for (int sm = wq; sm < 2 * NKS; sm += 4) {
        const int s = sm >> 1;
        const int m = sm & 1;
        const int grow = (r >> 3) * HH + hbase16 + m * 8 + (r & 7);
        const int k8 = s * 16 + (lane >> 5) * 8;
        const float* src = (k8 < IN_DIM)
            ? (Wih + (size_t)grow * IN_DIM + k8)
            : (Whh + (size_t)grow * HH + (k8 - IN_DIM));
        float w[8];
        *(float4*)&w[0] = *(const float4*)src;
        *(float4*)&w[4] = *(const float4*)(src + 4);
        f16x8 hv;
        #pragma unroll
        for (int j = 0; j < 8; ++j) hv[j] = (_Float16)w[j];
        *(f16x8*)(WAc + (size_t)s * 2048 + m * 1024 + lane * 16) = hv;
    }
}

// hbuf_l: [parity][grp=64][b=64][16B f16] (64KB/parity). Block tile owns
// grps 2*tile, 2*tile+1 (16 h-units). flags: 32 per layer, spread 128B.
template<int LAYER, int IN_DIM, int NKS, int KH>
__device__ void lstm_core(int tile,
                          const char* __restrict__ xTq,
                          const char* __restrict__ hbuf_prev, char* __restrict__ hbuf,
                          float* __restrict__ h2last, unsigned* __restrict__ flags,
                          const float* __restrict__ Wih, const float* __restrict__ Whh,
                          const float* __restrict__ bih, const float* __restrict__ bhh,
                          char* __restrict__ WAc, float* __restrict__ redbuf) {
    const int tid = threadIdx.x;
    const int lane = tid & 63;
    const int wq = tid >> 6;
    const int ntile = wq & 1;
    const int khalf = wq >> 1;
    const int lg = lane >> 5;
    const int b = ntile * 32 + (lane & 31);
    const int hbase16 = tile * 16;

    pack_weights<IN_DIM, NKS>(Wih, Whh, hbase16, WAc);

    float bias_v[32];
    float cst[8] = {0.f, 0.f, 0.f, 0.f, 0.f, 0.f, 0.f, 0.f};
    if (khalf == 0) {
        #pragma unroll
        for (int m = 0; m < 2; ++m)
            #pragma unroll
            for (int r = 0; r < 16; ++r) {
                const int grow = (r >> 2) * HH + hbase16 + m * 8 + (r & 3) + 4 * lg;
                bias_v[m * 16 + r] = bih[grow] + bhh[grow];
            }
    }
    __syncthreads();   // WA ready

    const char* wa = WAc + lane * 16;

    unsigned* const arr_own  = flags + (size_t)(LAYER * NBPL) * FLAG_STRIDE;
    const unsigned* arr_prev = (LAYER > 0) ? flags + (size_t)((LAYER - 1) * NBPL) * FLAG_STRIDE : arr_own;
    const unsigned* arr_next = (LAYER < 2) ? flags + (size_t)((LAYER + 1) * NBPL) * FLAG_STRIDE : arr_own;
    unsigned* const my_flag  = arr_own + (size_t)tile * FLAG_STRIDE;
    const int xoff = lg * 1024 + b * 16;

    for (int t = 0; t < TT; ++t) {
        f32x16 c0 = {0,0,0,0,0,0,0,0,0,0,0,0,0,0,0,0};
        f32x16 c1 = c0;
        const char* rb_h = hbuf + (size_t)(t & 1) * 65536 + xoff;            // h(t-1)
        const char* rb_x = hbuf_prev + (size_t)((t + 1) & 1) * 65536 + xoff; // x(t)=h_{l-1}(t)

        if (khalf == 0) {
            if (LAYER == 0) {
                const char* xq = xTq + (size_t)t * 8192 + xoff;
                #pragma unroll
                for (int s = 0; s < 4; ++s) {
                    f16x8 bv = *(const f16x8*)(xq + (size_t)s * 2048);
                    f16x8 a0 = *(const f16x8*)(wa + (size_t)s * 2048);
                    f16x8 a1 = *(const f16x8*)(wa + (size_t)s * 2048 + 1024);
                    c0 = MFMA_F16(a0, bv, c0, 0, 0, 0);
                    c1 = MFMA_F16(a1, bv, c1, 0, 0, 0);
                }
                if (t > 0) {
                    poll_ge32(arr_own, (unsigned)t);                  // h(t-1) ready
                    panel16<4>(rb_h, wa, c0, c1);                     // ring ksteps 4..19
                }
            } else {
                poll_ge32(arr_prev, (unsigned)(t + 1));               // x(t) ready
                panel32<0>(rb_x, wa, c0, c1);                         // x ksteps 0..31
            }
        } else {
            if (t > 0) {
                poll_ge32(arr_own, (unsigned)t);                      // h(t-1) ready
                if (LAYER == 0) panel16<20>(rb_h + 32768, wa, c0, c1);
                else            panel32<32>(rb_h, wa, c0, c1);
            }
        }

        if (khalf == 1) {
            float* pw = &redbuf[((size_t)ntile * 64 + lane) * 36];
            #pragma unroll
            for (int q = 0; q < 4; ++q) {
                float4 v; v.x = c0[q*4+0]; v.y = c0[q*4+1]; v.z = c0[q*4+2]; v.w = c0[q*4+3];
                *(float4*)(pw + q * 4) = v;
            }
            #pragma unroll
            for (int q = 0; q < 4; ++q) {
                float4 v; v.x = c1[q*4+0]; v.y = c1[q*4+1]; v.z = c1[q*4+2]; v.w = c1[q*4+3];
                *(float4*)(pw + 16 + q * 4) = v;
            }
        }
        __syncthreads();   // join gates + partials; own>=t now holds block-wide
        if (khalf == 0) {
            const float* pr = &redbuf[((size_t)ntile * 64 + lane) * 36];
            float prv[32];
            #pragma unroll
            for (int q = 0; q < 8; ++q)
                *(float4*)&prv[q * 4] = *(const float4*)(pr + q * 4);

            // back-pressure before overwriting h(t-2): next-layer x-readers done
            if (LAYER < 2 && t >= 2) poll_ge32(arr_next, (unsigned)(t - 1));

            #pragma unroll
            for (int m = 0; m < 2; ++m) {
                const f32x16& cs = (m == 0) ? c0 : c1;
                union { _Float16 h[4]; unsigned long long u; } hp;
                #pragma unroll
                for (int j = 0; j < 4; ++j) {
                    const float iv = sigmoidf_(cs[0 + j]  + prv[m*16 + 0 + j]  + bias_v[m*16 + 0 + j]);
                    const float fv = sigmoidf_(cs[4 + j]  + prv[m*16 + 4 + j]  + bias_v[m*16 + 4 + j]);
                    const float gv = tanhf   (cs[8 + j]  + prv[m*16 + 8 + j]  + bias_v[m*16 + 8 + j]);
                    const float ov = sigmoidf_(cs[12 + j] + prv[m*16 + 12 + j] + bias_v[m*16 + 12 + j]);
                    cst[m*4 + j] = fv * cst[m*4 + j] + iv * gv;
                    const float hv = ov * tanhf(cst[m*4 + j]);
                    hp.h[j] = (_Float16)hv;
                    if (LAYER == 2 && t == TT - 1)
                        storef_thru(h2last + (size_t)(hbase16 + m*8 + j + 4*lg) * 64 + b, hv);
                }
                // h(t) -> parity (t+1)&1, grp = tile*2+m, 4 f16 at byte lg*8
                char* d2 = hbuf + (size_t)((t + 1) & 1) * 65536
                         + (size_t)(tile * 2 + m) * 1024 + b * 16 + lg * 8;
                store8_thru(d2, hp.u);
            }
        }
        // publish: every wave drains its stores, then one flag store
        __builtin_amdgcn_s_waitcnt(0);
        __syncthreads();
        if (tid == 0) storeu_thru(my_flag, (unsigned)(t + 1));
    }
}

__global__ __launch_bounds__(256, 1) void lstm_wavefront(
    const char* __restrict__ xTq,
    char* __restrict__ hbuf0, char* __restrict__ hbuf1, char* __restrict__ hbuf2,
    float* __restrict__ h2last, unsigned* __restrict__ flags,
    const float* __restrict__ Wih0, const float* __restrict__ Whh0,
    const float* __restrict__ bih0, const float* __restrict__ bhh0,
    const float* __restrict__ Wih1, const float* __restrict__ Whh1,
    const float* __restrict__ bih1, const float* __restrict__ bhh1,
    const float* __restrict__ Wih2, const float* __restrict__ Whh2,
    const float* __restrict__ bih2, const float* __restrict__ bhh2,
    const float* __restrict__ fcw, const float* __restrict__ fcb,
    float* __restrict__ out) {

    __shared__ char WAc[64 * 2048];        // 128 KB: [kstep][m-tile][lane] f16 hi
    __shared__ float redbuf[2 * 64 * 36];  // 18 KB
    __shared__ float fcred[256];

    const int l = blockIdx.x >> 5;
    const int tile = blockIdx.x & 31;

    if (l == 0)
        lstm_core<0, II, 36, 20>(tile, xTq, nullptr, hbuf0, h2last, flags,
                                 Wih0, Whh0, bih0, bhh0, WAc, redbuf);
    else if (l == 1)
        lstm_core<1, HH, 64, 32>(tile, xTq, hbuf0, hbuf1, h2last, flags,
                                 Wih1, Whh1, bih1, bhh1, WAc, redbuf);
    else
        lstm_core<2, HH, 64, 32>(tile, xTq, hbuf1, hbuf2, h2last, flags,
                                 Wih2, Whh2, bih2, bhh2, WAc, redbuf);

    // final FC on h2[T-1]
    if (blockIdx.x == 0) {
        if (threadIdx.x < 64)
            poll_ge32(flags + (size_t)(2 * NBPL) * FLAG_STRIDE, (unsigned)TT);
        __syncthreads();
        const int tid = threadIdx.x;
        const int b = tid & 63, kq = tid >> 6;
        float s = 0.f;
        const float* hp = h2last + (size_t)kq * 128 * 64 + b;
        const float* wp = fcw + kq * 128;
        #pragma unroll 8
        for (int k = 0; k < 128; ++k)
            s = fmaf(loadf_byp(hp + (size_t)k * 64), wp[k], s);
        fcred[tid] = s;
        __syncthreads();
        if (tid < 64)
            out[tid] = fcred[tid] + fcred[64 + tid] + fcred[128 + tid] + fcred[192 + tid] + fcb[0];
    }
}

extern "C" void kernel_launch(void* const* d_in, const int* in_sizes, int n_in,
                              void* d_out, int out_size, void* d_ws, size_t ws_size,
                              hipStream_t stream) {
    (void)in_sizes; (void)n_in; (void)out_size; (void)ws_size;

    const float* x    = (const float*)d_in[0];
    const float* Wih0 = (const float*)d_in[1];
    const float* Whh0 = (const float*)d_in[2];
    const float* bih0 = (const float*)d_in[3];
    const float* bhh0 = (const float*)d_in[4];
    const float* Wih1 = (const float*)d_in[5];
    const float* Whh1 = (const float*)d_in[6];
    const float* bih1 = (const float*)d_in[7];
    const float* bhh1 = (const float*)d_in[8];
    const float* Wih2 = (const float*)d_in[9];
    const float* Whh2 = (const float*)d_in[10];
    const float* bih2 = (const float*)d_in[11];
    const float* bhh2 = (const float*)d_in[12];
    const float* fcw  = (const float*)d_in[13];
    const float* fcb  = (const float*)d_in[14];

    char* ws = (char*)d_ws;
    unsigned* flags = (unsigned*)ws;                       // 3*32*128B = 12 KB
    char* hbuf0   = ws + 65536;                            // 2*64KB = 128 KB each
    char* hbuf1   = hbuf0 + 2 * 64 * 64 * 16;
    char* hbuf2   = hbuf1 + 2 * 64 * 64 * 16;
    float* h2last = (float*)(hbuf2 + 2 * 64 * 64 * 16);    // 128 KB
    char* xTq     = (char*)h2last + 512 * 64 * 4;          // 4 MB

    hipError_t err = hipMemsetAsync(ws, 0, 65536, stream);
    (void)err;

    pack_x<<<TT, 256, 0, stream>>>(x, xTq);

    lstm_wavefront<<<NBLK, 256, 0, stream>>>(
        xTq, hbuf0, hbuf1, hbuf2, h2last, flags,
        Wih0, Whh0, bih0, bhh0,
        Wih1, Whh1, bih1, bhh1,
        Wih2, Whh2, bih2, bhh2,
        fcw, fcb, (float*)d_out);
}